// Round 3
// baseline (79.219 us; speedup 1.0000x reference)
//
#include <hip/hip_runtime.h>
#include <math.h>

// TropConv2D: out[b,ho,wo,f] = max_k(patch + w) - min_k(patch + w) + bias
// B=8, H=W=32, C=32, KH=KW=3, F=64, Ho=Wo=30, K=288. 7200 output pixels.
//
// R3 structure: K-split across waves, w in REGISTERS.
//   Block = 512 threads (8 waves), owns 8 consecutive pixels.
//   Wave v owns channel-chunk c in [4v, 4v+4) for all 9 taps -> 36 w floats
//   per lane (lane = filter), loaded coalesced once per block.
//   x reads are wave-uniform float4 global loads (broadcast, L1/L2-hot),
//   72 independent per wave -> deep ILP, no staging, no per-tap barrier.
//   Partial (max,min) per (pixel,f) combined via one 32 KB LDS pass +
//   ONE __syncthreads (R2 had 9 barriers + 2M ds_read_b32).

#define PPB 8     // pixels per block
#define NW  8     // waves per block (= K chunks of 4 channels)

__global__ __launch_bounds__(512) void trop_kernel(
    const float* __restrict__ x,     // (8,32,32,32)
    const float* __restrict__ w,     // (288,64)
    const float* __restrict__ bias,  // (64,)
    float* __restrict__ out)         // (7200,64)
{
    __shared__ float part[NW * PPB * 2 * 64];  // 32 KiB

    const int tid  = threadIdx.x;
    const int lane = tid & 63;   // filter
    const int wv   = tid >> 6;   // 0..7 : channel-chunk index
    const int pix0 = blockIdx.x * PPB;

    // --- w chunk into registers: wr[tap*4+j] = w[tap*32 + wv*4 + j][lane]
    float wr[36];
#pragma unroll
    for (int tap = 0; tap < 9; ++tap)
#pragma unroll
        for (int j = 0; j < 4; ++j)
            wr[tap * 4 + j] = w[(tap * 32 + wv * 4 + j) * 64 + lane];  // coalesced

    // --- per-pixel x base pointers (include my channel offset)
    const float* xb[PPB];
#pragma unroll
    for (int p = 0; p < PPB; ++p) {
        const int pid = pix0 + p;
        const int wo = pid % 30;
        const int t  = pid / 30;
        const int ho = t % 30;
        const int b  = t / 30;
        xb[p] = x + (((b * 32 + ho) * 32) + wo) * 32 + wv * 4;
    }

    float amax[PPB], amin[PPB];
#pragma unroll
    for (int p = 0; p < PPB; ++p) { amax[p] = -INFINITY; amin[p] = INFINITY; }

#pragma unroll
    for (int tap = 0; tap < 9; ++tap) {
        const int dy = tap / 3;
        const int dx = tap % 3;
        const int xo = (dy * 32 + dx) * 32;

        // 8 independent wave-uniform loads -> batched in flight
        float4 xv[PPB];
#pragma unroll
        for (int p = 0; p < PPB; ++p)
            xv[p] = *(const float4*)(xb[p] + xo);

#pragma unroll
        for (int p = 0; p < PPB; ++p) {
            const float s0 = xv[p].x + wr[tap * 4 + 0];
            const float s1 = xv[p].y + wr[tap * 4 + 1];
            const float s2 = xv[p].z + wr[tap * 4 + 2];
            const float s3 = xv[p].w + wr[tap * 4 + 3];
            amax[p] = fmaxf(fmaxf(fmaxf(fmaxf(amax[p], s0), s1), s2), s3);
            amin[p] = fminf(fminf(fminf(fminf(amin[p], s0), s1), s2), s3);
        }
    }

    // --- write partials: part[(wv*PPB + p)*2 + s][lane], lane-consecutive
#pragma unroll
    for (int p = 0; p < PPB; ++p) {
        part[((wv * PPB + p) * 2 + 0) * 64 + lane] = amax[p];
        part[((wv * PPB + p) * 2 + 1) * 64 + lane] = amin[p];
    }
    __syncthreads();

    // --- wave wv reduces pixel wv across the 8 chunk-partials
    {
        const int p = wv;
        float mx = -INFINITY, mn = INFINITY;
#pragma unroll
        for (int v = 0; v < NW; ++v) {
            mx = fmaxf(mx, part[((v * PPB + p) * 2 + 0) * 64 + lane]);
            mn = fminf(mn, part[((v * PPB + p) * 2 + 1) * 64 + lane]);
        }
        out[(pix0 + p) * 64 + lane] = mx - mn + bias[lane];  // coalesced 256B
    }
}

extern "C" void kernel_launch(void* const* d_in, const int* in_sizes, int n_in,
                              void* d_out, int out_size, void* d_ws, size_t ws_size,
                              hipStream_t stream) {
    const float* x    = (const float*)d_in[0];
    const float* w    = (const float*)d_in[1];
    const float* bias = (const float*)d_in[2];
    float* out = (float*)d_out;

    // 7200 pixels / 8 per block = 900 blocks of 8 waves
    trop_kernel<<<dim3(900), dim3(512), 0, stream>>>(x, w, bias, out);
}